// Round 1
// baseline (1608.341 us; speedup 1.0000x reference)
//
#include <hip/hip_runtime.h>

// Problem constants (B=2, S=2048, E=1024, H=16, HD=64)
constexpr int kB = 2;
constexpr int kS = 2048;
constexpr int kE = 1024;
constexpr int kH = 16;
constexpr int kF = 3 * kE;  // 3072
constexpr float kScale = 0.125f;  // HD^-0.5

#define TK 32
#define LDP 68  // padded LDS row (k-major tiles): 68*4B = 272B, 16B-aligned rows, low conflict

// ---------------------------------------------------------------------------
// C[64,64] = alpha * (A . B^T) + bias   — A:[64,K] k-major (lda), B:[64,K] k-major (ldb)
// Caller pre-offsets all pointers to the block's tile origin.
// ---------------------------------------------------------------------------
__device__ __forceinline__ void gemm_nt_body(
    const float* __restrict__ A, const float* __restrict__ Bm,
    const float* __restrict__ bias, float* __restrict__ C,
    int K, int lda, int ldb, int ldc, float alpha)
{
    __shared__ float As[TK][LDP];
    __shared__ float Bs[TK][LDP];
    const int tid = threadIdx.x;
    const int tx = tid & 15;
    const int ty = tid >> 4;
    const int lr = tid >> 3;        // 0..31
    const int lc = (tid & 7) << 2;  // 0,4,...,28

    float acc[4][4];
#pragma unroll
    for (int i = 0; i < 4; ++i)
#pragma unroll
        for (int j = 0; j < 4; ++j) acc[i][j] = 0.f;

    for (int k0 = 0; k0 < K; k0 += TK) {
        float4 a0 = *(const float4*)(A + (size_t)lr * lda + k0 + lc);
        float4 a1 = *(const float4*)(A + (size_t)(lr + 32) * lda + k0 + lc);
        float4 b0 = *(const float4*)(Bm + (size_t)lr * ldb + k0 + lc);
        float4 b1 = *(const float4*)(Bm + (size_t)(lr + 32) * ldb + k0 + lc);
        __syncthreads();
        As[lc + 0][lr] = a0.x; As[lc + 1][lr] = a0.y; As[lc + 2][lr] = a0.z; As[lc + 3][lr] = a0.w;
        As[lc + 0][lr + 32] = a1.x; As[lc + 1][lr + 32] = a1.y; As[lc + 2][lr + 32] = a1.z; As[lc + 3][lr + 32] = a1.w;
        Bs[lc + 0][lr] = b0.x; Bs[lc + 1][lr] = b0.y; Bs[lc + 2][lr] = b0.z; Bs[lc + 3][lr] = b0.w;
        Bs[lc + 0][lr + 32] = b1.x; Bs[lc + 1][lr + 32] = b1.y; Bs[lc + 2][lr + 32] = b1.z; Bs[lc + 3][lr + 32] = b1.w;
        __syncthreads();
#pragma unroll
        for (int kk = 0; kk < TK; ++kk) {
            float4 av = *(const float4*)&As[kk][ty << 2];
            float4 bv = *(const float4*)&Bs[kk][tx << 2];
            float a[4] = {av.x, av.y, av.z, av.w};
            float b[4] = {bv.x, bv.y, bv.z, bv.w};
#pragma unroll
            for (int i = 0; i < 4; ++i)
#pragma unroll
                for (int j = 0; j < 4; ++j)
                    acc[i][j] = fmaf(a[i], b[j], acc[i][j]);
        }
    }
#pragma unroll
    for (int i = 0; i < 4; ++i) {
        float4 v;
        v.x = acc[i][0] * alpha;
        v.y = acc[i][1] * alpha;
        v.z = acc[i][2] * alpha;
        v.w = acc[i][3] * alpha;
        if (bias) {
            v.x += bias[(tx << 2) + 0];
            v.y += bias[(tx << 2) + 1];
            v.z += bias[(tx << 2) + 2];
            v.w += bias[(tx << 2) + 3];
        }
        *(float4*)(C + (size_t)((ty << 2) + i) * ldc + (tx << 2)) = v;
    }
}

// ---------------------------------------------------------------------------
// C[64,64] = A . B   — A:[64,K] k-major (lda), B:[K,64] n-major (ldb)
// ---------------------------------------------------------------------------
__device__ __forceinline__ void gemm_nn_body(
    const float* __restrict__ A, const float* __restrict__ Bm,
    float* __restrict__ C, int K, int lda, int ldb, int ldc)
{
    __shared__ float As[TK][LDP];
    __shared__ float Bs[TK][LDP];
    const int tid = threadIdx.x;
    const int tx = tid & 15;
    const int ty = tid >> 4;
    const int lr = tid >> 3;         // 0..31
    const int lc = (tid & 7) << 2;   // 0..28
    const int kr = tid >> 4;         // 0..15
    const int nc = (tid & 15) << 2;  // 0..60

    float acc[4][4];
#pragma unroll
    for (int i = 0; i < 4; ++i)
#pragma unroll
        for (int j = 0; j < 4; ++j) acc[i][j] = 0.f;

    for (int k0 = 0; k0 < K; k0 += TK) {
        float4 a0 = *(const float4*)(A + (size_t)lr * lda + k0 + lc);
        float4 a1 = *(const float4*)(A + (size_t)(lr + 32) * lda + k0 + lc);
        float4 b0 = *(const float4*)(Bm + (size_t)(k0 + kr) * ldb + nc);
        float4 b1 = *(const float4*)(Bm + (size_t)(k0 + kr + 16) * ldb + nc);
        __syncthreads();
        As[lc + 0][lr] = a0.x; As[lc + 1][lr] = a0.y; As[lc + 2][lr] = a0.z; As[lc + 3][lr] = a0.w;
        As[lc + 0][lr + 32] = a1.x; As[lc + 1][lr + 32] = a1.y; As[lc + 2][lr + 32] = a1.z; As[lc + 3][lr + 32] = a1.w;
        *(float4*)&Bs[kr][nc] = b0;
        *(float4*)&Bs[kr + 16][nc] = b1;
        __syncthreads();
#pragma unroll
        for (int kk = 0; kk < TK; ++kk) {
            float4 av = *(const float4*)&As[kk][ty << 2];
            float4 bv = *(const float4*)&Bs[kk][tx << 2];
            float a[4] = {av.x, av.y, av.z, av.w};
            float b[4] = {bv.x, bv.y, bv.z, bv.w};
#pragma unroll
            for (int i = 0; i < 4; ++i)
#pragma unroll
                for (int j = 0; j < 4; ++j)
                    acc[i][j] = fmaf(a[i], b[j], acc[i][j]);
        }
    }
#pragma unroll
    for (int i = 0; i < 4; ++i) {
        float4 v = {acc[i][0], acc[i][1], acc[i][2], acc[i][3]};
        *(float4*)(C + (size_t)((ty << 2) + i) * ldc + (tx << 2)) = v;
    }
}

// ---------------------------------------------------------------------------
// Kernels
// ---------------------------------------------------------------------------

// qkv[n,f] = query[n,:] . in_proj_w[f,:] + in_proj_b[f]   (M=4096, N=3072, K=1024)
__global__ __launch_bounds__(256) void k_qkv(const float* __restrict__ query,
                                             const float* __restrict__ w,
                                             const float* __restrict__ bias,
                                             float* __restrict__ qkv)
{
    gemm_nt_body(query + (size_t)blockIdx.y * 64 * kE,
                 w + (size_t)blockIdx.x * 64 * kE,
                 bias + blockIdx.x * 64,
                 qkv + (size_t)blockIdx.y * 64 * kF + blockIdx.x * 64,
                 kE, kE, kE, kF, 1.0f);
}

// scores[z,q,k] = SCALE * q_head . k_head   (per z=(b,h): M=N=2048, K=64)
__global__ __launch_bounds__(256) void k_scores(const float* __restrict__ qkv,
                                                float* __restrict__ wts)
{
    const int z = blockIdx.z;
    const int b = z >> 4;
    const int h = z & 15;
    const float* Aq = qkv + (size_t)b * kS * kF + h * 64;          // q slice
    const float* Ak = qkv + (size_t)b * kS * kF + kE + h * 64;     // k slice
    float* C = wts + (size_t)z * kS * kS;
    gemm_nt_body(Aq + (size_t)blockIdx.y * 64 * kF,
                 Ak + (size_t)blockIdx.x * 64 * kF,
                 nullptr,
                 C + (size_t)blockIdx.y * 64 * kS + blockIdx.x * 64,
                 64, kF, kF, kS, kScale);
}

// In-place softmax over rows of 2048. One block per row.
__global__ __launch_bounds__(256) void k_softmax(float* __restrict__ wts)
{
    float* row = wts + (size_t)blockIdx.x * kS;
    const int tid = threadIdx.x;
    float4 v0 = *(float4*)(row + (tid << 2));
    float4 v1 = *(float4*)(row + 1024 + (tid << 2));

    float m = fmaxf(fmaxf(fmaxf(v0.x, v0.y), fmaxf(v0.z, v0.w)),
                    fmaxf(fmaxf(v1.x, v1.y), fmaxf(v1.z, v1.w)));
#pragma unroll
    for (int off = 32; off > 0; off >>= 1)
        m = fmaxf(m, __shfl_xor(m, off));
    __shared__ float redm[4];
    __shared__ float reds[4];
    if ((tid & 63) == 0) redm[tid >> 6] = m;
    __syncthreads();
    m = fmaxf(fmaxf(redm[0], redm[1]), fmaxf(redm[2], redm[3]));

    float e[8];
    e[0] = __expf(v0.x - m); e[1] = __expf(v0.y - m);
    e[2] = __expf(v0.z - m); e[3] = __expf(v0.w - m);
    e[4] = __expf(v1.x - m); e[5] = __expf(v1.y - m);
    e[6] = __expf(v1.z - m); e[7] = __expf(v1.w - m);
    float s = ((e[0] + e[1]) + (e[2] + e[3])) + ((e[4] + e[5]) + (e[6] + e[7]));
#pragma unroll
    for (int off = 32; off > 0; off >>= 1)
        s += __shfl_xor(s, off);
    if ((tid & 63) == 0) reds[tid >> 6] = s;
    __syncthreads();
    s = (reds[0] + reds[1]) + (reds[2] + reds[3]);

    const float inv = 1.0f / s;
    v0.x = e[0] * inv; v0.y = e[1] * inv; v0.z = e[2] * inv; v0.w = e[3] * inv;
    v1.x = e[4] * inv; v1.y = e[5] * inv; v1.z = e[6] * inv; v1.w = e[7] * inv;
    *(float4*)(row + (tid << 2)) = v0;
    *(float4*)(row + 1024 + (tid << 2)) = v1;
}

// attn_out[b, q, h*64+d] = sum_k W[z,q,k] * v[b,k,h,d]   (per z: M=2048, N=64, K=2048)
__global__ __launch_bounds__(256) void k_pv(const float* __restrict__ qkv,
                                            const float* __restrict__ wts,
                                            float* __restrict__ attn_out)
{
    const int z = blockIdx.z;
    const int b = z >> 4;
    const int h = z & 15;
    const float* A = wts + (size_t)z * kS * kS + (size_t)blockIdx.y * 64 * kS;
    const float* Bv = qkv + (size_t)b * kS * kF + 2 * kE + h * 64;
    float* C = attn_out + ((size_t)b * kS + blockIdx.y * 64) * kE + h * 64;
    gemm_nn_body(A, Bv, C, kS, kS, kF, kE);
}

// out[n,f] = attn_out[n,:] . out_proj_w[f,:] + out_proj_b[f]   (M=4096, N=1024, K=1024)
__global__ __launch_bounds__(256) void k_out(const float* __restrict__ attn_out,
                                             const float* __restrict__ w,
                                             const float* __restrict__ bias,
                                             float* __restrict__ out)
{
    gemm_nt_body(attn_out + (size_t)blockIdx.y * 64 * kE,
                 w + (size_t)blockIdx.x * 64 * kE,
                 bias + blockIdx.x * 64,
                 out + (size_t)blockIdx.y * 64 * kE + blockIdx.x * 64,
                 kE, kE, kE, kE, 1.0f);
}

// ---------------------------------------------------------------------------

extern "C" void kernel_launch(void* const* d_in, const int* in_sizes, int n_in,
                              void* d_out, int out_size, void* d_ws, size_t ws_size,
                              hipStream_t stream)
{
    const float* query = (const float*)d_in[0];
    // d_in[1] (key) and d_in[2] (value) are ignored by the reference module.
    const float* in_w  = (const float*)d_in[3];
    const float* in_b  = (const float*)d_in[4];
    const float* out_w = (const float*)d_in[5];
    const float* out_b = (const float*)d_in[6];

    float* out = (float*)d_out;                              // [2,2048,1024]
    float* wts = out + (size_t)kB * kS * kE;                 // [2,16,2048,2048]

    // workspace: qkv [4096,3072] fp32 (48 MB) + attn_out [4096,1024] fp32 (16 MB)
    float* qkv = (float*)d_ws;
    float* attn_out = qkv + (size_t)kB * kS * kF;

    dim3 blk(256);
    k_qkv<<<dim3(kF / 64, (kB * kS) / 64), blk, 0, stream>>>(query, in_w, in_b, qkv);
    k_scores<<<dim3(kS / 64, kS / 64, kB * kH), blk, 0, stream>>>(qkv, wts);
    k_softmax<<<dim3(kB * kH * kS), blk, 0, stream>>>(wts);
    k_pv<<<dim3(1, kS / 64, kB * kH), blk, 0, stream>>>(qkv, wts, attn_out);
    k_out<<<dim3(kE / 64, (kB * kS) / 64), blk, 0, stream>>>(attn_out, out_w, out_b, out);
}

// Round 2
// 863.206 us; speedup vs baseline: 1.8632x; 1.8632x over previous
//
#include <hip/hip_runtime.h>

// Problem: B=2, S=2048, E=1024, H=16, HD=64
constexpr int kB = 2;
constexpr int kS = 2048;
constexpr int kE = 1024;
constexpr int kF = 3 * kE;  // 3072

typedef __attribute__((ext_vector_type(8))) short short8;   // 8 bf16 (4 VGPRs) — MFMA A/B frag
typedef __attribute__((ext_vector_type(4))) float f32x4;    // MFMA C/D frag

__device__ __forceinline__ ushort f2bf_rne(float f) {
    uint u = __float_as_uint(f);
    return (ushort)((u + 0x7FFF + ((u >> 16) & 1)) >> 16);
}

// ---------------------------------------------------------------------------
// fp32 -> bf16 cast (RNE), 4 elements/thread
// ---------------------------------------------------------------------------
__global__ __launch_bounds__(256) void k_cast(const float* __restrict__ in,
                                              ushort* __restrict__ out, int n4)
{
    int i = blockIdx.x * 256 + threadIdx.x;
    if (i < n4) {
        float4 v = ((const float4*)in)[i];
        ushort4 o;
        o.x = f2bf_rne(v.x); o.y = f2bf_rne(v.y);
        o.z = f2bf_rne(v.z); o.w = f2bf_rne(v.w);
        ((ushort4*)out)[i] = o;
    }
}

// ---------------------------------------------------------------------------
// Stage a 64x64 bf16 tile (row stride gstride elems) into LDS [64][72]
// ---------------------------------------------------------------------------
__device__ __forceinline__ void stage64(ushort* __restrict__ Ls,
                                        const ushort* __restrict__ g,
                                        int gstride, int tid)
{
    int r = tid >> 3;
    int c = (tid & 7) << 3;
    *(uint4*)(Ls + r * 72 + c)        = *(const uint4*)(g + (size_t)r * gstride + c);
    *(uint4*)(Ls + (r + 32) * 72 + c) = *(const uint4*)(g + (size_t)(r + 32) * gstride + c);
}

#define FRAG72(Ls, row, koff) (*(const short8*)((Ls) + (size_t)(row) * 72 + (koff)))

// ---------------------------------------------------------------------------
// Generic bf16 MFMA GEMM-NT: C[M,N] = A[M,K] . B[N,K]^T + bias
// 128x128 tile, 4 waves (2x2), each wave 64x64 = 4x4 grid of 16x16x32 MFMAs.
// Cb!=null -> bf16 out (cols < qcols additionally scaled by 0.125 AFTER bias).
// ---------------------------------------------------------------------------
__global__ __launch_bounds__(256) void k_gemm(const ushort* __restrict__ A,
                                              const ushort* __restrict__ Bw,
                                              const float* __restrict__ bias,
                                              ushort* __restrict__ Cb,
                                              float* __restrict__ Cf,
                                              int K, int ldc, int qcols)
{
    __shared__ ushort As[128 * 40];  // rows m, 32 k (pad->40): 80B rows, 16B-mult
    __shared__ ushort Bs[128 * 40];
    const int tid = threadIdx.x;
    const int wave = tid >> 6, lane = tid & 63;
    const int quad = lane >> 4, c16 = lane & 15;
    const int wm = (wave >> 1) * 64, wn = (wave & 1) * 64;
    const int row0 = blockIdx.y * 128, col0 = blockIdx.x * 128;

    f32x4 acc[4][4];
#pragma unroll
    for (int i = 0; i < 4; ++i)
#pragma unroll
        for (int j = 0; j < 4; ++j) acc[i][j] = (f32x4){0.f, 0.f, 0.f, 0.f};

    const int sr = tid >> 2;
    const int sq = (tid & 3) << 3;

    for (int k0 = 0; k0 < K; k0 += 32) {
        __syncthreads();
        *(uint4*)(As + sr * 40 + sq)        = *(const uint4*)(A + (size_t)(row0 + sr) * K + k0 + sq);
        *(uint4*)(As + (sr + 64) * 40 + sq) = *(const uint4*)(A + (size_t)(row0 + sr + 64) * K + k0 + sq);
        *(uint4*)(Bs + sr * 40 + sq)        = *(const uint4*)(Bw + (size_t)(col0 + sr) * K + k0 + sq);
        *(uint4*)(Bs + (sr + 64) * 40 + sq) = *(const uint4*)(Bw + (size_t)(col0 + sr + 64) * K + k0 + sq);
        __syncthreads();

        short8 af[4], bf[4];
#pragma unroll
        for (int mt = 0; mt < 4; ++mt)
            af[mt] = *(const short8*)(As + (size_t)(wm + mt * 16 + c16) * 40 + quad * 8);
#pragma unroll
        for (int nt = 0; nt < 4; ++nt)
            bf[nt] = *(const short8*)(Bs + (size_t)(wn + nt * 16 + c16) * 40 + quad * 8);
#pragma unroll
        for (int mt = 0; mt < 4; ++mt)
#pragma unroll
            for (int nt = 0; nt < 4; ++nt)
                acc[mt][nt] = __builtin_amdgcn_mfma_f32_16x16x32_bf16(af[mt], bf[nt], acc[mt][nt], 0, 0, 0);
    }

#pragma unroll
    for (int nt = 0; nt < 4; ++nt) {
        const int colg = col0 + wn + nt * 16 + c16;
        const float bv = bias[colg];
        const float sc = (colg < qcols) ? 0.125f : 1.0f;
#pragma unroll
        for (int mt = 0; mt < 4; ++mt)
#pragma unroll
            for (int r = 0; r < 4; ++r) {
                const int rowg = row0 + wm + mt * 16 + quad * 4 + r;
                float v = acc[mt][nt][r] + bv;
                if (Cb) Cb[(size_t)rowg * ldc + colg] = f2bf_rne(v * sc);
                else    Cf[(size_t)rowg * ldc + colg] = v;
            }
    }
}

// ---------------------------------------------------------------------------
// Transpose V slice of qkv_bf16 into vT[b][h*64+d][s]
// ---------------------------------------------------------------------------
__global__ __launch_bounds__(256) void k_vt(const ushort* __restrict__ qkvb,
                                            ushort* __restrict__ vT)
{
    const int b = blockIdx.z, si = blockIdx.y, di = blockIdx.x;
    __shared__ ushort Ls[64 * 72];
    const int tid = threadIdx.x;
    stage64(Ls, qkvb + ((size_t)(b * kS + si * 64)) * kF + 2 * kE + di * 64, kF, tid);
    __syncthreads();
    const int dd = tid >> 3;
    const int s8 = (tid & 7) << 3;
#pragma unroll
    for (int it = 0; it < 2; ++it) {
        const int d = dd + it * 32;
        uint o[4];
#pragma unroll
        for (int i = 0; i < 4; ++i) {
            uint lo = Ls[(s8 + 2 * i) * 72 + d];
            uint hi = Ls[(s8 + 2 * i + 1) * 72 + d];
            o[i] = lo | (hi << 16);
        }
        *(uint4*)(vT + ((size_t)(b * kE + di * 64 + d)) * kS + si * 64 + s8) = *(uint4*)o;
    }
}

// ---------------------------------------------------------------------------
// Fused attention: scores (bf16 MFMA) + two-pass softmax + PV.
// Block: 64 q-rows of one (b,h). Wave w owns q-rows w*16..w*16+15.
// Pass 1: running row max m / sum l over all 32 k-tiles (scores discarded).
// Pass 2: recompute S, write p=exp(s-m)/l to attn_weights (fp32), accumulate
//         P.V via MFMA (P round-trips LDS: C/D layout -> A layout).
// ---------------------------------------------------------------------------
__global__ __launch_bounds__(256) void k_attn(const ushort* __restrict__ qkvb,
                                              const ushort* __restrict__ vT,
                                              float* __restrict__ wts,
                                              ushort* __restrict__ aob)
{
    __shared__ ushort Qs[64 * 72];
    __shared__ ushort Ks[64 * 72];
    __shared__ ushort Vts[64 * 72];
    __shared__ ushort Ps[64 * 72];

    const int tid = threadIdx.x;
    const int wave = tid >> 6, lane = tid & 63;
    const int quad = lane >> 4, c16 = lane & 15;
    const int z = blockIdx.y;
    const int b = z >> 4, h = z & 15;
    const int Rq = blockIdx.x * 64;

    const ushort* qg  = qkvb + ((size_t)(b * kS + Rq)) * kF + h * 64;        // q (pre-scaled)
    const ushort* kg  = qkvb + ((size_t)b * kS) * kF + kE + h * 64;          // k
    const ushort* vtg = vT + ((size_t)(b * kE + h * 64)) * kS;               // v^T rows d
    float* wrow = wts + ((size_t)(z * kS) + Rq + wave * 16) * kS;

    stage64(Qs, qg, kF, tid);
    __syncthreads();
    const short8 qa0 = FRAG72(Qs, wave * 16 + c16, quad * 8);
    const short8 qa1 = FRAG72(Qs, wave * 16 + c16, quad * 8 + 32);

    float m[4] = {-1e30f, -1e30f, -1e30f, -1e30f};
    float l[4] = {0.f, 0.f, 0.f, 0.f};

    // ---- pass 1: stats ----
    for (int j = 0; j < 32; ++j) {
        __syncthreads();
        stage64(Ks, kg + (size_t)j * 64 * kF, kF, tid);
        __syncthreads();
        f32x4 s[4];
#pragma unroll
        for (int ct = 0; ct < 4; ++ct) {
            short8 b0 = FRAG72(Ks, ct * 16 + c16, quad * 8);
            short8 b1 = FRAG72(Ks, ct * 16 + c16, quad * 8 + 32);
            f32x4 a = (f32x4){0.f, 0.f, 0.f, 0.f};
            a = __builtin_amdgcn_mfma_f32_16x16x32_bf16(qa0, b0, a, 0, 0, 0);
            a = __builtin_amdgcn_mfma_f32_16x16x32_bf16(qa1, b1, a, 0, 0, 0);
            s[ct] = a;
        }
#pragma unroll
        for (int r = 0; r < 4; ++r) {
            float tm = fmaxf(fmaxf(s[0][r], s[1][r]), fmaxf(s[2][r], s[3][r]));
            tm = fmaxf(tm, __shfl_xor(tm, 1));
            tm = fmaxf(tm, __shfl_xor(tm, 2));
            tm = fmaxf(tm, __shfl_xor(tm, 4));
            tm = fmaxf(tm, __shfl_xor(tm, 8));
            const float mn = fmaxf(m[r], tm);
            float sum = __expf(s[0][r] - mn) + __expf(s[1][r] - mn)
                      + __expf(s[2][r] - mn) + __expf(s[3][r] - mn);
            sum += __shfl_xor(sum, 1);
            sum += __shfl_xor(sum, 2);
            sum += __shfl_xor(sum, 4);
            sum += __shfl_xor(sum, 8);
            l[r] = l[r] * __expf(m[r] - mn) + sum;
            m[r] = mn;
        }
    }
    float invl[4];
#pragma unroll
    for (int r = 0; r < 4; ++r) invl[r] = 1.0f / l[r];

    // ---- pass 2: p-write + PV ----
    f32x4 o[4];
#pragma unroll
    for (int i = 0; i < 4; ++i) o[i] = (f32x4){0.f, 0.f, 0.f, 0.f};

    for (int j = 0; j < 32; ++j) {
        __syncthreads();
        stage64(Ks, kg + (size_t)j * 64 * kF, kF, tid);
        stage64(Vts, vtg + j * 64, kS, tid);
        __syncthreads();
        f32x4 s[4];
#pragma unroll
        for (int ct = 0; ct < 4; ++ct) {
            short8 b0 = FRAG72(Ks, ct * 16 + c16, quad * 8);
            short8 b1 = FRAG72(Ks, ct * 16 + c16, quad * 8 + 32);
            f32x4 a = (f32x4){0.f, 0.f, 0.f, 0.f};
            a = __builtin_amdgcn_mfma_f32_16x16x32_bf16(qa0, b0, a, 0, 0, 0);
            a = __builtin_amdgcn_mfma_f32_16x16x32_bf16(qa1, b1, a, 0, 0, 0);
            s[ct] = a;
        }
#pragma unroll
        for (int ct = 0; ct < 4; ++ct)
#pragma unroll
            for (int r = 0; r < 4; ++r) {
                const float p = __expf(s[ct][r] - m[r]) * invl[r];
                wrow[(size_t)(quad * 4 + r) * kS + j * 64 + ct * 16 + c16] = p;
                Ps[(size_t)(wave * 16 + quad * 4 + r) * 72 + ct * 16 + c16] = f2bf_rne(p);
            }
        __syncthreads();  // Ps write->read ordering (intra-wave stripe, keep safe)
        const short8 pa0 = FRAG72(Ps, wave * 16 + c16, quad * 8);
        const short8 pa1 = FRAG72(Ps, wave * 16 + c16, quad * 8 + 32);
#pragma unroll
        for (int ct2 = 0; ct2 < 4; ++ct2) {
            short8 v0 = FRAG72(Vts, ct2 * 16 + c16, quad * 8);
            short8 v1 = FRAG72(Vts, ct2 * 16 + c16, quad * 8 + 32);
            o[ct2] = __builtin_amdgcn_mfma_f32_16x16x32_bf16(pa0, v0, o[ct2], 0, 0, 0);
            o[ct2] = __builtin_amdgcn_mfma_f32_16x16x32_bf16(pa1, v1, o[ct2], 0, 0, 0);
        }
    }

#pragma unroll
    for (int ct2 = 0; ct2 < 4; ++ct2)
#pragma unroll
        for (int r = 0; r < 4; ++r) {
            const size_t row = (size_t)(b * kS + Rq + wave * 16 + quad * 4 + r);
            aob[row * kE + h * 64 + ct2 * 16 + c16] = f2bf_rne(o[ct2][r]);
        }
}

// ---------------------------------------------------------------------------

extern "C" void kernel_launch(void* const* d_in, const int* in_sizes, int n_in,
                              void* d_out, int out_size, void* d_ws, size_t ws_size,
                              hipStream_t stream)
{
    const float* query = (const float*)d_in[0];
    const float* in_w  = (const float*)d_in[3];
    const float* in_b  = (const float*)d_in[4];
    const float* out_w = (const float*)d_in[5];
    const float* out_b = (const float*)d_in[6];

    float* out = (float*)d_out;                      // [2,2048,1024]
    float* wts = out + (size_t)kB * kS * kE;         // [2,16,2048,2048]

    constexpr size_t MB = 1u << 20;
    char* w = (char*)d_ws;
    ushort* qbf  = (ushort*)(w);             // query bf16      [4096,1024]  8 MB
    ushort* wbfi = (ushort*)(w + 8 * MB);    // in_proj_w bf16  [3072,1024]  6 MB
    ushort* wbfo = (ushort*)(w + 14 * MB);   // out_proj_w bf16 [1024,1024]  2 MB
    ushort* qkvb = (ushort*)(w + 16 * MB);   // qkv bf16        [4096,3072] 24 MB
    ushort* vT   = (ushort*)(w + 40 * MB);   // v^T bf16   [2,1024 d,2048 s] 8 MB
    ushort* aob  = (ushort*)(w + 48 * MB);   // attn_out bf16   [4096,1024]  8 MB

    dim3 blk(256);
    k_cast<<<dim3((4096 * 1024 / 4 + 255) / 256), blk, 0, stream>>>(query, qbf, 4096 * 1024 / 4);
    k_cast<<<dim3((3072 * 1024 / 4 + 255) / 256), blk, 0, stream>>>(in_w, wbfi, 3072 * 1024 / 4);
    k_cast<<<dim3((1024 * 1024 / 4 + 255) / 256), blk, 0, stream>>>(out_w, wbfo, 1024 * 1024 / 4);

    // qkv = query . in_proj_w^T + b  (q section scaled by 0.125), bf16 out
    k_gemm<<<dim3(kF / 128, 4096 / 128), blk, 0, stream>>>(qbf, wbfi, in_b, qkvb, nullptr, kE, kF, kE);

    k_vt<<<dim3(16, 32, 2), blk, 0, stream>>>(qkvb, vT);

    k_attn<<<dim3(kS / 64, kB * 16), blk, 0, stream>>>(qkvb, vT, wts, aob);

    // out = attn_out . out_proj_w^T + b, fp32 out
    k_gemm<<<dim3(kE / 128, 4096 / 128), blk, 0, stream>>>(aob, wbfo, out_b, nullptr, out, kE, kE, 0);
}